// Round 1
// baseline (1060.312 us; speedup 1.0000x reference)
//
#include <hip/hip_runtime.h>
#include <hip/hip_bf16.h>
#include <math.h>

#define IN_CH   128
#define HC      256   // HEADS*OUT_CH
#define OUT_C   64
#define NEG_SLOPE 0.2f

// ---------------------------------------------------------------------------
// GEMM: out[n,256] = x[n,128] @ W[128,256]   (f32 vector, W row L1-resident)
// block = 256 threads = 4 rows x 64 col-quads; x rows staged in LDS.
// ---------------------------------------------------------------------------
__global__ __launch_bounds__(256) void k_gemm(const float* __restrict__ x,
                                              const float* __restrict__ W,
                                              float* __restrict__ out, int n) {
    __shared__ float xs[4 * IN_CH];
    const int tid  = threadIdx.x;
    const int row0 = blockIdx.x * 4;
    // stage 4 rows (512 floats) via 256 float2 loads (clamped for safety)
    {
        int g2   = row0 * 64 + tid;           // float2 index
        int maxg = n * 64 - 1;
        g2 = g2 > maxg ? maxg : g2;
        ((float2*)xs)[tid] = ((const float2*)x)[g2];
    }
    __syncthreads();
    const int c4 = tid & 63;   // column quad 0..63  -> cols 4*c4..4*c4+3
    const int r  = tid >> 6;   // row within tile 0..3
    const float*  xrow = xs + r * IN_CH;
    const float4* Wv   = (const float4*)W;
    float4 acc = make_float4(0.f, 0.f, 0.f, 0.f);
#pragma unroll 8
    for (int k = 0; k < IN_CH; ++k) {
        const float  xv = xrow[k];
        const float4 w  = Wv[k * 64 + c4];
        acc.x = fmaf(xv, w.x, acc.x);
        acc.y = fmaf(xv, w.y, acc.y);
        acc.z = fmaf(xv, w.z, acc.z);
        acc.w = fmaf(xv, w.w, acc.w);
    }
    if (row0 + r < n)
        ((float4*)(out + (size_t)(row0 + r) * HC))[c4] = acc;
}

// ---------------------------------------------------------------------------
// CSR build: zero / histogram / 3-phase scan / scatter (int atomics only)
// ---------------------------------------------------------------------------
__global__ void k_zero(int* p, int n) {
    int i = blockIdx.x * 256 + threadIdx.x;
    if (i < n) p[i] = 0;
}

__global__ void k_hist(const int* __restrict__ dst, int E, int* __restrict__ deg) {
    int i = blockIdx.x * 256 + threadIdx.x;
    if (i < E) atomicAdd(&deg[dst[i]], 1);
}

__global__ __launch_bounds__(1024) void k_scanA(const int* __restrict__ deg, int n,
                                                int* __restrict__ incl,
                                                int* __restrict__ bsum) {
    __shared__ int sm[1024];
    const int t = threadIdx.x;
    const int i = blockIdx.x * 1024 + t;
    sm[t] = (i < n) ? deg[i] : 0;
    for (int off = 1; off < 1024; off <<= 1) {
        __syncthreads();
        int u = (t >= off) ? sm[t - off] : 0;
        __syncthreads();
        sm[t] += u;
    }
    if (i < n) incl[i] = sm[t];
    if (t == 1023) bsum[blockIdx.x] = sm[1023];
}

__global__ __launch_bounds__(1024) void k_scanB(int* __restrict__ bsum, int nb) {
    __shared__ int sm[1024];
    const int t = threadIdx.x;
    sm[t] = (t < nb) ? bsum[t] : 0;
    for (int off = 1; off < 1024; off <<= 1) {
        __syncthreads();
        int u = (t >= off) ? sm[t - off] : 0;
        __syncthreads();
        sm[t] += u;
    }
    if (t < nb) bsum[t] = sm[t];
}

__global__ void k_scanC(const int* __restrict__ incl, const int* __restrict__ deg,
                        const int* __restrict__ bsum, int n,
                        int* __restrict__ offs, int* __restrict__ cursor) {
    int i = blockIdx.x * 256 + threadIdx.x;
    if (i < n) {
        int b    = i >> 10;
        int base = (b > 0) ? bsum[b - 1] : 0;
        int excl = base + incl[i] - deg[i];
        offs[i]   = excl;
        cursor[i] = excl;
    }
}

__global__ void k_scatter(const int* __restrict__ src, const int* __restrict__ dst,
                          int E, int* __restrict__ cursor, int* __restrict__ csr_src) {
    int i = blockIdx.x * 256 + threadIdx.x;
    if (i < E) {
        int d   = dst[i];
        int pos = atomicAdd(&cursor[d], 1);
        csr_src[pos] = src[i];
    }
}

// ---------------------------------------------------------------------------
// Fused per-node GATv2 aggregation, one wave per destination node.
// Online softmax (flash-style): running m, l per head; O accumulator in regs.
// lane l owns channels 4l..4l+3; head = l/16.
// ---------------------------------------------------------------------------
__global__ __launch_bounds__(256) void k_agg(const float* __restrict__ xl,
                                             const float* __restrict__ xr,
                                             const float* __restrict__ att,
                                             const int* __restrict__ offs,
                                             const int* __restrict__ deg,
                                             const int* __restrict__ csr_src,
                                             int n, float* __restrict__ out,
                                             int selfLoop,
                                             const float* __restrict__ theta,
                                             int accumulate) {
    const int lane = threadIdx.x & 63;
    const int node = blockIdx.x * 4 + (threadIdx.x >> 6);
    if (node >= n) return;

    const float4 attv = ((const float4*)att)[lane];
    const float4 xrv  = ((const float4*)(xr + (size_t)node * HC))[lane];
    const int start = offs[node];
    const int cnt   = deg[node];
    const int total = cnt + selfLoop;

    float m = -INFINITY, l = 0.f;
    float4 O = make_float4(0.f, 0.f, 0.f, 0.f);

    float4 xlNext = make_float4(0.f, 0.f, 0.f, 0.f);
    if (total > 0) {
        int s0 = selfLoop ? node : csr_src[start];
        xlNext = ((const float4*)(xl + (size_t)s0 * HC))[lane];
    }

    for (int i = 0; i < total; ++i) {
        float4 xlv = xlNext;
        int j = i + 1;
        if (j < total) {                       // prefetch next source row
            int sN = csr_src[start + j - selfLoop];
            xlNext = ((const float4*)(xl + (size_t)sN * HC))[lane];
        }
        // score partial: att . leaky_relu(xl[src] + xr[dst])
        float zx = xlv.x + xrv.x, zy = xlv.y + xrv.y;
        float zz = xlv.z + xrv.z, zw = xlv.w + xrv.w;
        float rx = fmaxf(zx, 0.f) + NEG_SLOPE * fminf(zx, 0.f);
        float ry = fmaxf(zy, 0.f) + NEG_SLOPE * fminf(zy, 0.f);
        float rz = fmaxf(zz, 0.f) + NEG_SLOPE * fminf(zz, 0.f);
        float rw = fmaxf(zw, 0.f) + NEG_SLOPE * fminf(zw, 0.f);
        float part = attv.x * rx + attv.y * ry + attv.z * rz + attv.w * rw;
        // reduce within 16-lane head group (all 16 lanes end with the sum)
        part += __shfl_xor(part, 1);
        part += __shfl_xor(part, 2);
        part += __shfl_xor(part, 4);
        part += __shfl_xor(part, 8);
        // online softmax update
        float mN = fmaxf(m, part);
        float sc = __expf(m - mN);      // m=-inf first iter -> 0
        float p  = __expf(part - mN);
        l = l * sc + p;
        O.x = O.x * sc + p * xlv.x;
        O.y = O.y * sc + p * xlv.y;
        O.z = O.z * sc + p * xlv.z;
        O.w = O.w * sc + p * xlv.w;
        m = mN;
    }

    float inv = (l > 0.f) ? 1.f / l : 0.f;   // l==0: node with no in-edges -> 0
    float vx = O.x * inv, vy = O.y * inv, vz = O.z * inv, vw = O.w * inv;
    // mean over heads: sum lanes l, l^16, l^32, l^48
    vx += __shfl_xor(vx, 16); vx += __shfl_xor(vx, 32);
    vy += __shfl_xor(vy, 16); vy += __shfl_xor(vy, 32);
    vz += __shfl_xor(vz, 16); vz += __shfl_xor(vz, 32);
    vw += __shfl_xor(vw, 16); vw += __shfl_xor(vw, 32);

    if (lane < 16) {
        float4 r = make_float4(0.25f * vx, 0.25f * vy, 0.25f * vz, 0.25f * vw);
        float4* op = (float4*)(out + (size_t)node * OUT_C);
        if (accumulate) {
            float sg = 1.f / (1.f + __expf(-theta[0]));
            float4 cur = op[lane];
            r.x = fmaf(sg, r.x, cur.x);
            r.y = fmaf(sg, r.y, cur.y);
            r.z = fmaf(sg, r.z, cur.z);
            r.w = fmaf(sg, r.w, cur.w);
        }
        op[lane] = r;
    }
}

// ---------------------------------------------------------------------------
extern "C" void kernel_launch(void* const* d_in, const int* in_sizes, int n_in,
                              void* d_out, int out_size, void* d_ws, size_t ws_size,
                              hipStream_t stream) {
    const float* x     = (const float*)d_in[0];
    const int*   e1    = (const int*)d_in[1];   // [2,E1] flat: [0..E1)=src, [E1..2E1)=dst
    const int*   e2    = (const int*)d_in[2];
    const float* Wl    = (const float*)d_in[3];
    const float* Wr0   = (const float*)d_in[4];
    const float* Wr1   = (const float*)d_in[5];
    const float* att0  = (const float*)d_in[6];
    const float* att1  = (const float*)d_in[7];
    const float* theta = (const float*)d_in[8];

    const int n  = in_sizes[0] / IN_CH;  // 50000
    const int E1 = in_sizes[1] / 2;
    const int E2 = in_sizes[2] / 2;
    float* out = (float*)d_out;

    // workspace carve-up (all 256B aligned)
    char* w = (char*)d_ws;
    auto alloc = [&](size_t bytes) -> char* {
        char* p = w;
        w += (bytes + 255) & ~(size_t)255;
        return p;
    };
    float* xl     = (float*)alloc((size_t)n * HC * 4);
    float* xr     = (float*)alloc((size_t)n * HC * 4);
    const int Em  = E1 > E2 ? E1 : E2;
    int*   csr    = (int*)alloc((size_t)Em * 4);
    int*   deg    = (int*)alloc((size_t)n * 4);
    int*   incl   = (int*)alloc((size_t)n * 4);
    int*   offs   = (int*)alloc((size_t)n * 4);
    int*   cursor = (int*)alloc((size_t)n * 4);
    int*   bsum   = (int*)alloc(4096);

    const int gRows  = (n + 3) / 4;        // one wave per node, 4 waves/block
    const int gNodes = (n + 255) / 256;
    const int nScan  = (n + 1023) / 1024;

    // shared left projection
    k_gemm<<<gRows, 256, 0, stream>>>(x, Wl, xl, n);

    // ---- hop 0 (self loops virtual) ----
    k_gemm<<<gRows, 256, 0, stream>>>(x, Wr0, xr, n);
    k_zero<<<gNodes, 256, 0, stream>>>(deg, n);
    k_hist<<<(E1 + 255) / 256, 256, 0, stream>>>(e1 + E1, E1, deg);
    k_scanA<<<nScan, 1024, 0, stream>>>(deg, n, incl, bsum);
    k_scanB<<<1, 1024, 0, stream>>>(bsum, nScan);
    k_scanC<<<gNodes, 256, 0, stream>>>(incl, deg, bsum, n, offs, cursor);
    k_scatter<<<(E1 + 255) / 256, 256, 0, stream>>>(e1, e1 + E1, E1, cursor, csr);
    k_agg<<<gRows, 256, 0, stream>>>(xl, xr, att0, offs, deg, csr, n, out,
                                     /*selfLoop=*/1, theta, /*accumulate=*/0);

    // ---- hop 1 (no self loops, gated accumulate) ----
    k_gemm<<<gRows, 256, 0, stream>>>(x, Wr1, xr, n);
    k_zero<<<gNodes, 256, 0, stream>>>(deg, n);
    k_hist<<<(E2 + 255) / 256, 256, 0, stream>>>(e2 + E2, E2, deg);
    k_scanA<<<nScan, 1024, 0, stream>>>(deg, n, incl, bsum);
    k_scanB<<<1, 1024, 0, stream>>>(bsum, nScan);
    k_scanC<<<gNodes, 256, 0, stream>>>(incl, deg, bsum, n, offs, cursor);
    k_scatter<<<(E2 + 255) / 256, 256, 0, stream>>>(e2, e2 + E2, E2, cursor, csr);
    k_agg<<<gRows, 256, 0, stream>>>(xl, xr, att1, offs, deg, csr, n, out,
                                     /*selfLoop=*/0, theta, /*accumulate=*/1);
}

// Round 2
// 672.569 us; speedup vs baseline: 1.5765x; 1.5765x over previous
//
#include <hip/hip_runtime.h>
#include <hip/hip_bf16.h>
#include <math.h>

#define IN_CH   128
#define HC      256   // HEADS*OUT_C
#define OUT_C   64
#define NEG_SLOPE 0.2f

// ---------------------------------------------------------------------------
// GEMM: out[n,256] = x[n,128] @ W[128,256]  (f32 vector)
// block = 256 threads; tile = 32 rows x 256 cols; 8 rows per thread.
// Per k-chunk(4): 4 W float4 loads + 8 ds_read_b128 (wave-uniform) + 128 FMA.
// ---------------------------------------------------------------------------
__global__ __launch_bounds__(256) void k_gemm(const float* __restrict__ x,
                                              const float* __restrict__ W,
                                              float* __restrict__ out, int n) {
    __shared__ float xs[32 * IN_CH];          // 16 KB
    const int tid  = threadIdx.x;
    const int row0 = blockIdx.x * 32;
    // stage 32 rows = 4096 floats = 1024 float4, 4 per thread (clamped)
    {
        const float4* x4 = (const float4*)x;
        const int maxg = n * (IN_CH / 4) - 1;
        float4* xs4 = (float4*)xs;
#pragma unroll
        for (int i = 0; i < 4; ++i) {
            int g = row0 * (IN_CH / 4) + i * 256 + tid;
            xs4[i * 256 + tid] = x4[g > maxg ? maxg : g];
        }
    }
    __syncthreads();
    const int c4 = tid & 63;   // column quad 0..63
    const int rg = tid >> 6;   // wave id 0..3 (uniform within wave)
    const float4* Wv = (const float4*)W;
    float4 acc[8];
#pragma unroll
    for (int j = 0; j < 8; ++j) acc[j] = make_float4(0.f, 0.f, 0.f, 0.f);

    for (int k = 0; k < IN_CH; k += 4) {
        const float4 w0 = Wv[(k + 0) * 64 + c4];
        const float4 w1 = Wv[(k + 1) * 64 + c4];
        const float4 w2 = Wv[(k + 2) * 64 + c4];
        const float4 w3 = Wv[(k + 3) * 64 + c4];
#pragma unroll
        for (int j = 0; j < 8; ++j) {
            const float4 xv = *(const float4*)(xs + (j * 4 + rg) * IN_CH + k);
            acc[j].x = fmaf(xv.x, w0.x, acc[j].x);
            acc[j].y = fmaf(xv.x, w0.y, acc[j].y);
            acc[j].z = fmaf(xv.x, w0.z, acc[j].z);
            acc[j].w = fmaf(xv.x, w0.w, acc[j].w);
            acc[j].x = fmaf(xv.y, w1.x, acc[j].x);
            acc[j].y = fmaf(xv.y, w1.y, acc[j].y);
            acc[j].z = fmaf(xv.y, w1.z, acc[j].z);
            acc[j].w = fmaf(xv.y, w1.w, acc[j].w);
            acc[j].x = fmaf(xv.z, w2.x, acc[j].x);
            acc[j].y = fmaf(xv.z, w2.y, acc[j].y);
            acc[j].z = fmaf(xv.z, w2.z, acc[j].z);
            acc[j].w = fmaf(xv.z, w2.w, acc[j].w);
            acc[j].x = fmaf(xv.w, w3.x, acc[j].x);
            acc[j].y = fmaf(xv.w, w3.y, acc[j].y);
            acc[j].z = fmaf(xv.w, w3.z, acc[j].z);
            acc[j].w = fmaf(xv.w, w3.w, acc[j].w);
        }
    }
#pragma unroll
    for (int j = 0; j < 8; ++j) {
        const int row = row0 + j * 4 + rg;
        if (row < n)
            ((float4*)(out + (size_t)row * HC))[c4] = acc[j];
    }
}

// ---------------------------------------------------------------------------
// CSR build: zero / histogram / 3-phase scan / scatter (int atomics only)
// ---------------------------------------------------------------------------
__global__ void k_zero(int* p, int n) {
    int i = blockIdx.x * 256 + threadIdx.x;
    if (i < n) p[i] = 0;
}

__global__ void k_hist(const int* __restrict__ dst, int E, int* __restrict__ deg) {
    int i = blockIdx.x * 256 + threadIdx.x;
    if (i < E) atomicAdd(&deg[dst[i]], 1);
}

__global__ __launch_bounds__(1024) void k_scanA(const int* __restrict__ deg, int n,
                                                int* __restrict__ incl,
                                                int* __restrict__ bsum) {
    __shared__ int sm[1024];
    const int t = threadIdx.x;
    const int i = blockIdx.x * 1024 + t;
    sm[t] = (i < n) ? deg[i] : 0;
    for (int off = 1; off < 1024; off <<= 1) {
        __syncthreads();
        int u = (t >= off) ? sm[t - off] : 0;
        __syncthreads();
        sm[t] += u;
    }
    if (i < n) incl[i] = sm[t];
    if (t == 1023) bsum[blockIdx.x] = sm[1023];
}

__global__ __launch_bounds__(1024) void k_scanB(int* __restrict__ bsum, int nb) {
    __shared__ int sm[1024];
    const int t = threadIdx.x;
    sm[t] = (t < nb) ? bsum[t] : 0;
    for (int off = 1; off < 1024; off <<= 1) {
        __syncthreads();
        int u = (t >= off) ? sm[t - off] : 0;
        __syncthreads();
        sm[t] += u;
    }
    if (t < nb) bsum[t] = sm[t];
}

__global__ void k_scanC(const int* __restrict__ incl, const int* __restrict__ deg,
                        const int* __restrict__ bsum, int n,
                        int* __restrict__ offs, int* __restrict__ cursor) {
    int i = blockIdx.x * 256 + threadIdx.x;
    if (i < n) {
        int b    = i >> 10;
        int base = (b > 0) ? bsum[b - 1] : 0;
        int excl = base + incl[i] - deg[i];
        offs[i]   = excl;
        cursor[i] = excl;
    }
}

__global__ void k_scatter(const int* __restrict__ src, const int* __restrict__ dst,
                          int E, int* __restrict__ cursor, int* __restrict__ csr_src) {
    int i = blockIdx.x * 256 + threadIdx.x;
    if (i < E) {
        int d   = dst[i];
        int pos = atomicAdd(&cursor[d], 1);
        csr_src[pos] = src[i];
    }
}

// ---------------------------------------------------------------------------
// Fused per-node GATv2 aggregation, one wave per destination node.
// Online softmax (flash-style): running m, l per head; O accumulator in regs.
// lane l owns channels 4l..4l+3; head = l/16.
// ---------------------------------------------------------------------------
__global__ __launch_bounds__(256) void k_agg(const float* __restrict__ xl,
                                             const float* __restrict__ xr,
                                             const float* __restrict__ att,
                                             const int* __restrict__ offs,
                                             const int* __restrict__ deg,
                                             const int* __restrict__ csr_src,
                                             int n, float* __restrict__ out,
                                             int selfLoop,
                                             const float* __restrict__ theta,
                                             int accumulate) {
    const int lane = threadIdx.x & 63;
    const int node = blockIdx.x * 4 + (threadIdx.x >> 6);
    if (node >= n) return;

    const float4 attv = ((const float4*)att)[lane];
    const float4 xrv  = ((const float4*)(xr + (size_t)node * HC))[lane];
    const int start = offs[node];
    const int cnt   = deg[node];
    const int total = cnt + selfLoop;

    float m = -INFINITY, l = 0.f;
    float4 O = make_float4(0.f, 0.f, 0.f, 0.f);

    float4 xlNext = make_float4(0.f, 0.f, 0.f, 0.f);
    if (total > 0) {
        int s0 = selfLoop ? node : csr_src[start];
        xlNext = ((const float4*)(xl + (size_t)s0 * HC))[lane];
    }

    for (int i = 0; i < total; ++i) {
        float4 xlv = xlNext;
        int j = i + 1;
        if (j < total) {                       // prefetch next source row
            int sN = csr_src[start + j - selfLoop];
            xlNext = ((const float4*)(xl + (size_t)sN * HC))[lane];
        }
        // score partial: att . leaky_relu(xl[src] + xr[dst])
        float zx = xlv.x + xrv.x, zy = xlv.y + xrv.y;
        float zz = xlv.z + xrv.z, zw = xlv.w + xrv.w;
        float rx = fmaxf(zx, 0.f) + NEG_SLOPE * fminf(zx, 0.f);
        float ry = fmaxf(zy, 0.f) + NEG_SLOPE * fminf(zy, 0.f);
        float rz = fmaxf(zz, 0.f) + NEG_SLOPE * fminf(zz, 0.f);
        float rw = fmaxf(zw, 0.f) + NEG_SLOPE * fminf(zw, 0.f);
        float part = attv.x * rx + attv.y * ry + attv.z * rz + attv.w * rw;
        // reduce within 16-lane head group (all 16 lanes end with the sum)
        part += __shfl_xor(part, 1);
        part += __shfl_xor(part, 2);
        part += __shfl_xor(part, 4);
        part += __shfl_xor(part, 8);
        // online softmax update
        float mN = fmaxf(m, part);
        float sc = __expf(m - mN);      // m=-inf first iter -> 0
        float p  = __expf(part - mN);
        l = l * sc + p;
        O.x = O.x * sc + p * xlv.x;
        O.y = O.y * sc + p * xlv.y;
        O.z = O.z * sc + p * xlv.z;
        O.w = O.w * sc + p * xlv.w;
        m = mN;
    }

    float inv = (l > 0.f) ? 1.f / l : 0.f;   // l==0: node with no in-edges -> 0
    float vx = O.x * inv, vy = O.y * inv, vz = O.z * inv, vw = O.w * inv;
    // mean over heads: sum lanes l, l^16, l^32, l^48
    vx += __shfl_xor(vx, 16); vx += __shfl_xor(vx, 32);
    vy += __shfl_xor(vy, 16); vy += __shfl_xor(vy, 32);
    vz += __shfl_xor(vz, 16); vz += __shfl_xor(vz, 32);
    vw += __shfl_xor(vw, 16); vw += __shfl_xor(vw, 32);

    if (lane < 16) {
        float4 r = make_float4(0.25f * vx, 0.25f * vy, 0.25f * vz, 0.25f * vw);
        float4* op = (float4*)(out + (size_t)node * OUT_C);
        if (accumulate) {
            float sg = 1.f / (1.f + __expf(-theta[0]));
            float4 cur = op[lane];
            r.x = fmaf(sg, r.x, cur.x);
            r.y = fmaf(sg, r.y, cur.y);
            r.z = fmaf(sg, r.z, cur.z);
            r.w = fmaf(sg, r.w, cur.w);
        }
        op[lane] = r;
    }
}

// ---------------------------------------------------------------------------
extern "C" void kernel_launch(void* const* d_in, const int* in_sizes, int n_in,
                              void* d_out, int out_size, void* d_ws, size_t ws_size,
                              hipStream_t stream) {
    const float* x     = (const float*)d_in[0];
    const int*   e1    = (const int*)d_in[1];   // [2,E1] flat: [0..E1)=src, [E1..2E1)=dst
    const int*   e2    = (const int*)d_in[2];
    const float* Wl    = (const float*)d_in[3];
    const float* Wr0   = (const float*)d_in[4];
    const float* Wr1   = (const float*)d_in[5];
    const float* att0  = (const float*)d_in[6];
    const float* att1  = (const float*)d_in[7];
    const float* theta = (const float*)d_in[8];

    const int n  = in_sizes[0] / IN_CH;  // 50000
    const int E1 = in_sizes[1] / 2;
    const int E2 = in_sizes[2] / 2;
    float* out = (float*)d_out;

    // workspace carve-up (all 256B aligned)
    char* w = (char*)d_ws;
    auto alloc = [&](size_t bytes) -> char* {
        char* p = w;
        w += (bytes + 255) & ~(size_t)255;
        return p;
    };
    float* xl     = (float*)alloc((size_t)n * HC * 4);
    float* xr     = (float*)alloc((size_t)n * HC * 4);
    const int Em  = E1 > E2 ? E1 : E2;
    int*   csr    = (int*)alloc((size_t)Em * 4);
    int*   deg    = (int*)alloc((size_t)n * 4);
    int*   incl   = (int*)alloc((size_t)n * 4);
    int*   offs   = (int*)alloc((size_t)n * 4);
    int*   cursor = (int*)alloc((size_t)n * 4);
    int*   bsum   = (int*)alloc(4096);

    const int gGemm  = (n + 31) / 32;      // 32 rows per block
    const int gAgg   = (n + 3) / 4;        // one wave per node, 4 waves/block
    const int gNodes = (n + 255) / 256;
    const int nScan  = (n + 1023) / 1024;

    // shared left projection
    k_gemm<<<gGemm, 256, 0, stream>>>(x, Wl, xl, n);

    // ---- hop 0 (self loops virtual) ----
    k_gemm<<<gGemm, 256, 0, stream>>>(x, Wr0, xr, n);
    k_zero<<<gNodes, 256, 0, stream>>>(deg, n);
    k_hist<<<(E1 + 255) / 256, 256, 0, stream>>>(e1 + E1, E1, deg);
    k_scanA<<<nScan, 1024, 0, stream>>>(deg, n, incl, bsum);
    k_scanB<<<1, 1024, 0, stream>>>(bsum, nScan);
    k_scanC<<<gNodes, 256, 0, stream>>>(incl, deg, bsum, n, offs, cursor);
    k_scatter<<<(E1 + 255) / 256, 256, 0, stream>>>(e1, e1 + E1, E1, cursor, csr);
    k_agg<<<gAgg, 256, 0, stream>>>(xl, xr, att0, offs, deg, csr, n, out,
                                    /*selfLoop=*/1, theta, /*accumulate=*/0);

    // ---- hop 1 (no self loops, gated accumulate) ----
    k_gemm<<<gGemm, 256, 0, stream>>>(x, Wr1, xr, n);
    k_zero<<<gNodes, 256, 0, stream>>>(deg, n);
    k_hist<<<(E2 + 255) / 256, 256, 0, stream>>>(e2 + E2, E2, deg);
    k_scanA<<<nScan, 1024, 0, stream>>>(deg, n, incl, bsum);
    k_scanB<<<1, 1024, 0, stream>>>(bsum, nScan);
    k_scanC<<<gNodes, 256, 0, stream>>>(incl, deg, bsum, n, offs, cursor);
    k_scatter<<<(E2 + 255) / 256, 256, 0, stream>>>(e2, e2 + E2, E2, cursor, csr);
    k_agg<<<gAgg, 256, 0, stream>>>(xl, xr, att1, offs, deg, csr, n, out,
                                    /*selfLoop=*/0, theta, /*accumulate=*/1);
}

// Round 4
// 664.203 us; speedup vs baseline: 1.5964x; 1.0126x over previous
//
#include <hip/hip_runtime.h>
#include <hip/hip_bf16.h>
#include <math.h>

#define IN_CH   128
#define HC      256   // HEADS*OUT_C
#define OUT_C   64
#define NEG_SLOPE 0.2f

// ---------------------------------------------------------------------------
// GEMM x3: out[y][n,256] = x[n,128] @ W[y][128,256]  (f32 vector)
// block = 256 threads; tile = 32 rows x 256 cols; 8 rows per thread.
// blockIdx.y selects which projection (Wl / Wr0 / Wr1).
// ---------------------------------------------------------------------------
__global__ __launch_bounds__(256) void k_gemm3(const float* __restrict__ x,
                                               const float* __restrict__ W0,
                                               const float* __restrict__ W1,
                                               const float* __restrict__ W2,
                                               float* __restrict__ o0,
                                               float* __restrict__ o1,
                                               float* __restrict__ o2, int n) {
    const float* W;
    float* out;
    switch (blockIdx.y) {
        case 0:  W = W0; out = o0; break;
        case 1:  W = W1; out = o1; break;
        default: W = W2; out = o2; break;
    }
    __shared__ float xs[32 * IN_CH];          // 16 KB
    const int tid  = threadIdx.x;
    const int row0 = blockIdx.x * 32;
    {
        const float4* x4 = (const float4*)x;
        const int maxg = n * (IN_CH / 4) - 1;
        float4* xs4 = (float4*)xs;
#pragma unroll
        for (int i = 0; i < 4; ++i) {
            int g = row0 * (IN_CH / 4) + i * 256 + tid;
            xs4[i * 256 + tid] = x4[g > maxg ? maxg : g];
        }
    }
    __syncthreads();
    const int c4 = tid & 63;
    const int rg = tid >> 6;
    const float4* Wv = (const float4*)W;
    float4 acc[8];
#pragma unroll
    for (int j = 0; j < 8; ++j) acc[j] = make_float4(0.f, 0.f, 0.f, 0.f);

    for (int k = 0; k < IN_CH; k += 4) {
        const float4 w0 = Wv[(k + 0) * 64 + c4];
        const float4 w1 = Wv[(k + 1) * 64 + c4];
        const float4 w2 = Wv[(k + 2) * 64 + c4];
        const float4 w3 = Wv[(k + 3) * 64 + c4];
#pragma unroll
        for (int j = 0; j < 8; ++j) {
            const float4 xv = *(const float4*)(xs + (j * 4 + rg) * IN_CH + k);
            acc[j].x = fmaf(xv.x, w0.x, acc[j].x);
            acc[j].y = fmaf(xv.x, w0.y, acc[j].y);
            acc[j].z = fmaf(xv.x, w0.z, acc[j].z);
            acc[j].w = fmaf(xv.x, w0.w, acc[j].w);
            acc[j].x = fmaf(xv.y, w1.x, acc[j].x);
            acc[j].y = fmaf(xv.y, w1.y, acc[j].y);
            acc[j].z = fmaf(xv.y, w1.z, acc[j].z);
            acc[j].w = fmaf(xv.y, w1.w, acc[j].w);
            acc[j].x = fmaf(xv.z, w2.x, acc[j].x);
            acc[j].y = fmaf(xv.z, w2.y, acc[j].y);
            acc[j].z = fmaf(xv.z, w2.z, acc[j].z);
            acc[j].w = fmaf(xv.z, w2.w, acc[j].w);
            acc[j].x = fmaf(xv.w, w3.x, acc[j].x);
            acc[j].y = fmaf(xv.w, w3.y, acc[j].y);
            acc[j].z = fmaf(xv.w, w3.z, acc[j].z);
            acc[j].w = fmaf(xv.w, w3.w, acc[j].w);
        }
    }
#pragma unroll
    for (int j = 0; j < 8; ++j) {
        const int row = row0 + j * 4 + rg;
        if (row < n)
            ((float4*)(out + (size_t)row * HC))[c4] = acc[j];
    }
}

// ---------------------------------------------------------------------------
// Joint CSR build for BOTH hops: deg/offs/cursor are length 2n
// (hop0 at [0,n), hop1 at [n,2n)); single csr buffer of E1+E2 entries.
// ---------------------------------------------------------------------------
__global__ void k_zero(int* p, int n) {
    int i = blockIdx.x * 256 + threadIdx.x;
    if (i < n) p[i] = 0;
}

__global__ void k_hist2(const int* __restrict__ dst1, int E1,
                        const int* __restrict__ dst2, int E2,
                        int n, int* __restrict__ deg) {
    int i = blockIdx.x * 256 + threadIdx.x;
    if (i < E1) atomicAdd(&deg[dst1[i]], 1);
    else if (i < E1 + E2) atomicAdd(&deg[n + dst2[i - E1]], 1);
}

__global__ __launch_bounds__(1024) void k_scanA(const int* __restrict__ deg, int n,
                                                int* __restrict__ incl,
                                                int* __restrict__ bsum) {
    __shared__ int sm[1024];
    const int t = threadIdx.x;
    const int i = blockIdx.x * 1024 + t;
    sm[t] = (i < n) ? deg[i] : 0;
    for (int off = 1; off < 1024; off <<= 1) {
        __syncthreads();
        int u = (t >= off) ? sm[t - off] : 0;
        __syncthreads();
        sm[t] += u;
    }
    if (i < n) incl[i] = sm[t];
    if (t == 1023) bsum[blockIdx.x] = sm[1023];
}

__global__ __launch_bounds__(1024) void k_scanB(int* __restrict__ bsum, int nb) {
    __shared__ int sm[1024];
    const int t = threadIdx.x;
    sm[t] = (t < nb) ? bsum[t] : 0;
    for (int off = 1; off < 1024; off <<= 1) {
        __syncthreads();
        int u = (t >= off) ? sm[t - off] : 0;
        __syncthreads();
        sm[t] += u;
    }
    if (t < nb) bsum[t] = sm[t];
}

// NOTE: incl may alias cursor — each thread reads incl[i] before writing
// cursor[i] (same address, same thread, program order). offs must be distinct.
__global__ void k_scanC(const int* __restrict__ incl, const int* __restrict__ deg,
                        const int* __restrict__ bsum, int n,
                        int* __restrict__ offs, int* cursor) {
    int i = blockIdx.x * 256 + threadIdx.x;
    if (i < n) {
        int b    = i >> 10;
        int base = (b > 0) ? bsum[b - 1] : 0;
        int excl = base + incl[i] - deg[i];
        offs[i]   = excl;
        cursor[i] = excl;
    }
}

__global__ void k_scatter2(const int* __restrict__ src1, const int* __restrict__ dst1, int E1,
                           const int* __restrict__ src2, const int* __restrict__ dst2, int E2,
                           int n, int* __restrict__ cursor, int* __restrict__ csr_src) {
    int i = blockIdx.x * 256 + threadIdx.x;
    if (i < E1) {
        int pos = atomicAdd(&cursor[dst1[i]], 1);
        csr_src[pos] = src1[i];
    } else if (i < E1 + E2) {
        int j = i - E1;
        int pos = atomicAdd(&cursor[n + dst2[j]], 1);
        csr_src[pos] = src2[j];
    }
}

// ---------------------------------------------------------------------------
// Fused per-node GATv2 aggregation, one wave per destination node.
// No online max (softmax is shift-invariant; scores are O(1..10), clamp@60
// guards overflow). 4-deep gather pipeline for memory-level parallelism.
// lane l owns channels 4l..4l+3; head = l/16.
// ---------------------------------------------------------------------------
__global__ __launch_bounds__(256) void k_agg(const float* __restrict__ xl,
                                             const float* __restrict__ xr,
                                             const float* __restrict__ att,
                                             const int* __restrict__ offs,
                                             const int* __restrict__ deg,
                                             const int* __restrict__ csr_src,
                                             int n, float* __restrict__ out,
                                             int selfLoop,
                                             const float* __restrict__ theta,
                                             int accumulate) {
    const int lane = threadIdx.x & 63;
    const int node = blockIdx.x * 4 + (threadIdx.x >> 6);
    if (node >= n) return;

    const float4 attv = ((const float4*)att)[lane];
    const float4 xrv  = ((const float4*)(xr + (size_t)node * HC))[lane];
    const int start2 = offs[node] - selfLoop;   // edge i: src = (i==0&&selfLoop)?node:csr[start2+i]
    const int total  = deg[node] + selfLoop;

    float l = 0.f;
    float4 O = make_float4(0.f, 0.f, 0.f, 0.f);

    auto ld = [&](int i) -> float4 {
        int s = (selfLoop && i == 0) ? node : csr_src[start2 + i];
        return ((const float4*)(xl + (size_t)s * HC))[lane];
    };
    auto process = [&](const float4& cur) {
        float zx = cur.x + xrv.x, zy = cur.y + xrv.y;
        float zz = cur.z + xrv.z, zw = cur.w + xrv.w;
        float rx = fmaxf(zx, 0.f) + NEG_SLOPE * fminf(zx, 0.f);
        float ry = fmaxf(zy, 0.f) + NEG_SLOPE * fminf(zy, 0.f);
        float rz = fmaxf(zz, 0.f) + NEG_SLOPE * fminf(zz, 0.f);
        float rw = fmaxf(zw, 0.f) + NEG_SLOPE * fminf(zw, 0.f);
        float part = attv.x * rx + attv.y * ry + attv.z * rz + attv.w * rw;
        part += __shfl_xor(part, 1);
        part += __shfl_xor(part, 2);
        part += __shfl_xor(part, 4);
        part += __shfl_xor(part, 8);
        float p = __expf(fminf(part, 60.f));
        l += p;
        O.x = fmaf(p, cur.x, O.x);
        O.y = fmaf(p, cur.y, O.y);
        O.z = fmaf(p, cur.z, O.z);
        O.w = fmaf(p, cur.w, O.w);
    };

    float4 b0 = make_float4(0.f, 0.f, 0.f, 0.f), b1 = b0, b2 = b0, b3 = b0;
    if (0 < total) b0 = ld(0);
    if (1 < total) b1 = ld(1);
    if (2 < total) b2 = ld(2);
    if (3 < total) b3 = ld(3);

    int i = 0;
    for (; i + 4 <= total; i += 4) {
        float4 c0 = b0, c1 = b1, c2 = b2, c3 = b3;
        if (i + 4 < total) b0 = ld(i + 4);
        if (i + 5 < total) b1 = ld(i + 5);
        if (i + 6 < total) b2 = ld(i + 6);
        if (i + 7 < total) b3 = ld(i + 7);
        process(c0);
        process(c1);
        process(c2);
        process(c3);
    }
    const int rem = total - i;
    if (rem > 0) process(b0);
    if (rem > 1) process(b1);
    if (rem > 2) process(b2);

    float inv = (l > 0.f) ? 1.f / l : 0.f;   // no in-edges -> 0
    float vx = O.x * inv, vy = O.y * inv, vz = O.z * inv, vw = O.w * inv;
    vx += __shfl_xor(vx, 16); vx += __shfl_xor(vx, 32);
    vy += __shfl_xor(vy, 16); vy += __shfl_xor(vy, 32);
    vz += __shfl_xor(vz, 16); vz += __shfl_xor(vz, 32);
    vw += __shfl_xor(vw, 16); vw += __shfl_xor(vw, 32);

    if (lane < 16) {
        float4 r = make_float4(0.25f * vx, 0.25f * vy, 0.25f * vz, 0.25f * vw);
        float4* op = (float4*)(out + (size_t)node * OUT_C);
        if (accumulate) {
            float sg = 1.f / (1.f + __expf(-theta[0]));
            float4 cur = op[lane];
            r.x = fmaf(sg, r.x, cur.x);
            r.y = fmaf(sg, r.y, cur.y);
            r.z = fmaf(sg, r.z, cur.z);
            r.w = fmaf(sg, r.w, cur.w);
        }
        op[lane] = r;
    }
}

// ---------------------------------------------------------------------------
extern "C" void kernel_launch(void* const* d_in, const int* in_sizes, int n_in,
                              void* d_out, int out_size, void* d_ws, size_t ws_size,
                              hipStream_t stream) {
    const float* x     = (const float*)d_in[0];
    const int*   e1    = (const int*)d_in[1];   // [2,E1] flat: [0..E1)=src, [E1..2E1)=dst
    const int*   e2    = (const int*)d_in[2];
    const float* Wl    = (const float*)d_in[3];
    const float* Wr0   = (const float*)d_in[4];
    const float* Wr1   = (const float*)d_in[5];
    const float* att0  = (const float*)d_in[6];
    const float* att1  = (const float*)d_in[7];
    const float* theta = (const float*)d_in[8];

    const int n  = in_sizes[0] / IN_CH;  // 50000
    const int E1 = in_sizes[1] / 2;
    const int E2 = in_sizes[2] / 2;
    float* out = (float*)d_out;

    char* w = (char*)d_ws;
    auto alloc = [&](size_t bytes) -> char* {
        char* p = w;
        w += (bytes + 255) & ~(size_t)255;
        return p;
    };
    const size_t projB = (size_t)n * HC * 4;
    // 3-buffer layout needs: 3*proj + csr + 3*2n ints + bsum
    const size_t need3 = 3 * ((projB + 255) & ~(size_t)255)
                       + (((size_t)(E1 + E2) * 4 + 255) & ~(size_t)255)
                       + 3 * (((size_t)2 * n * 4 + 255) & ~(size_t)255) + 4096;
    const bool threeBuf = ws_size >= need3;

    float* xl  = (float*)alloc(projB);
    float* xr0 = (float*)alloc(projB);
    float* xr1 = threeBuf ? (float*)alloc(projB) : xr0;   // fallback: reuse
    int* csr    = (int*)alloc((size_t)(E1 + E2) * 4);
    int* deg    = (int*)alloc((size_t)2 * n * 4);
    int* offs   = (int*)alloc((size_t)2 * n * 4);
    int* cursor = (int*)alloc((size_t)2 * n * 4);   // also serves as incl (scanA out, scanC in-place)
    int* bsum   = (int*)alloc(4096);

    const int gGemm  = (n + 31) / 32;
    const int gAgg   = (n + 3) / 4;
    const int n2     = 2 * n;
    const int gN2    = (n2 + 255) / 256;
    const int nScan  = (n2 + 1023) / 1024;
    const int gE     = (E1 + E2 + 255) / 256;

    // joint CSR build (independent of projections)
    k_zero<<<gN2, 256, 0, stream>>>(deg, n2);
    k_hist2<<<gE, 256, 0, stream>>>(e1 + E1, E1, e2 + E2, E2, n, deg);
    k_scanA<<<nScan, 1024, 0, stream>>>(deg, n2, cursor, bsum);
    k_scanB<<<1, 1024, 0, stream>>>(bsum, nScan);
    k_scanC<<<gN2, 256, 0, stream>>>(cursor, deg, bsum, n2, offs, cursor);
    k_scatter2<<<gE, 256, 0, stream>>>(e1, e1 + E1, E1, e2, e2 + E2, E2, n, cursor, csr);

    if (threeBuf) {
        k_gemm3<<<dim3(gGemm, 3), 256, 0, stream>>>(x, Wl, Wr0, Wr1, xl, xr0, xr1, n);
        k_agg<<<gAgg, 256, 0, stream>>>(xl, xr0, att0, offs, deg, csr, n, out,
                                        /*selfLoop=*/1, theta, /*accumulate=*/0);
        k_agg<<<gAgg, 256, 0, stream>>>(xl, xr1, att1, offs + n, deg + n, csr, n, out,
                                        /*selfLoop=*/0, theta, /*accumulate=*/1);
    } else {
        k_gemm3<<<dim3(gGemm, 2), 256, 0, stream>>>(x, Wl, Wr0, Wr0, xl, xr0, xr0, n);
        k_agg<<<gAgg, 256, 0, stream>>>(xl, xr0, att0, offs, deg, csr, n, out,
                                        /*selfLoop=*/1, theta, /*accumulate=*/0);
        k_gemm3<<<dim3(gGemm, 1), 256, 0, stream>>>(x, Wr1, Wr1, Wr1, xr0, xr0, xr0, n);
        k_agg<<<gAgg, 256, 0, stream>>>(xl, xr0, att1, offs + n, deg + n, csr, n, out,
                                        /*selfLoop=*/0, theta, /*accumulate=*/1);
    }
}

// Round 6
// 606.637 us; speedup vs baseline: 1.7479x; 1.0949x over previous
//
#include <hip/hip_runtime.h>
#include <hip/hip_bf16.h>
#include <math.h>

#define IN_CH   128
#define HC      256   // HEADS*OUT_C
#define OUT_C   64
#define NEG_SLOPE 0.2f

// ===========================================================================
// Device building blocks
// ===========================================================================

// GEMM tile: out[32 rows x 256 cols] = x @ W, one block, bx = row-tile index.
__device__ __forceinline__ void dev_gemm(const float* __restrict__ x,
                                         const float* __restrict__ W,
                                         float* __restrict__ out, int n,
                                         int bx, float* xs) {
    const int tid  = threadIdx.x;
    const int row0 = bx * 32;
    {
        const float4* x4 = (const float4*)x;
        const int maxg = n * (IN_CH / 4) - 1;
        float4* xs4 = (float4*)xs;
#pragma unroll
        for (int i = 0; i < 4; ++i) {
            int g = row0 * (IN_CH / 4) + i * 256 + tid;
            xs4[i * 256 + tid] = x4[g > maxg ? maxg : g];
        }
    }
    __syncthreads();
    const int c4 = tid & 63;
    const int rg = tid >> 6;
    const float4* Wv = (const float4*)W;
    float4 acc[8];
#pragma unroll
    for (int j = 0; j < 8; ++j) acc[j] = make_float4(0.f, 0.f, 0.f, 0.f);

    for (int k = 0; k < IN_CH; k += 4) {
        const float4 w0 = Wv[(k + 0) * 64 + c4];
        const float4 w1 = Wv[(k + 1) * 64 + c4];
        const float4 w2 = Wv[(k + 2) * 64 + c4];
        const float4 w3 = Wv[(k + 3) * 64 + c4];
#pragma unroll
        for (int j = 0; j < 8; ++j) {
            const float4 xv = *(const float4*)(xs + (j * 4 + rg) * IN_CH + k);
            acc[j].x = fmaf(xv.x, w0.x, acc[j].x);
            acc[j].y = fmaf(xv.x, w0.y, acc[j].y);
            acc[j].z = fmaf(xv.x, w0.z, acc[j].z);
            acc[j].w = fmaf(xv.x, w0.w, acc[j].w);
            acc[j].x = fmaf(xv.y, w1.x, acc[j].x);
            acc[j].y = fmaf(xv.y, w1.y, acc[j].y);
            acc[j].z = fmaf(xv.y, w1.z, acc[j].z);
            acc[j].w = fmaf(xv.y, w1.w, acc[j].w);
            acc[j].x = fmaf(xv.z, w2.x, acc[j].x);
            acc[j].y = fmaf(xv.z, w2.y, acc[j].y);
            acc[j].z = fmaf(xv.z, w2.z, acc[j].z);
            acc[j].w = fmaf(xv.z, w2.w, acc[j].w);
            acc[j].x = fmaf(xv.w, w3.x, acc[j].x);
            acc[j].y = fmaf(xv.w, w3.y, acc[j].y);
            acc[j].z = fmaf(xv.w, w3.z, acc[j].z);
            acc[j].w = fmaf(xv.w, w3.w, acc[j].w);
        }
    }
#pragma unroll
    for (int j = 0; j < 8; ++j) {
        const int row = row0 + j * 4 + rg;
        if (row < n)
            ((float4*)(out + (size_t)row * HC))[c4] = acc[j];
    }
}

// Scatter one hop: edge i -> csr[cursor[base+dst[i]]++] = src[i]; grid-stride.
__device__ __forceinline__ void dev_scatter(const int* __restrict__ src,
                                            const int* __restrict__ dst, int E,
                                            int* cursor, int base,
                                            int* __restrict__ csr,
                                            int bid, int nB) {
    for (int i = bid * 256 + threadIdx.x; i < E; i += nB * 256) {
        int pos = atomicAdd(&cursor[base + dst[i]], 1);
        csr[pos] = src[i];
    }
}

// Per-node GATv2 aggregation (flat softmax + 4-deep gather pipeline).
__device__ __forceinline__ void dev_agg(const float* __restrict__ xl,
                                        const float* __restrict__ xr,
                                        const float* __restrict__ att,
                                        const int* __restrict__ offs,
                                        const int* __restrict__ deg,
                                        const int* __restrict__ csr_src,
                                        int n, float* __restrict__ out,
                                        int selfLoop,
                                        const float* __restrict__ theta,
                                        int accumulate, int bid) {
    const int lane = threadIdx.x & 63;
    const int node = bid * 4 + (threadIdx.x >> 6);
    if (node >= n) return;

    const float4 attv = ((const float4*)att)[lane];
    const float4 xrv  = ((const float4*)(xr + (size_t)node * HC))[lane];
    const int start2 = offs[node] - selfLoop;
    const int total  = deg[node] + selfLoop;

    float l = 0.f;
    float4 O = make_float4(0.f, 0.f, 0.f, 0.f);

    auto ld = [&](int i) -> float4 {
        int s = (selfLoop && i == 0) ? node : csr_src[start2 + i];
        return ((const float4*)(xl + (size_t)s * HC))[lane];
    };
    auto process = [&](const float4& cur) {
        float zx = cur.x + xrv.x, zy = cur.y + xrv.y;
        float zz = cur.z + xrv.z, zw = cur.w + xrv.w;
        float rx = fmaxf(zx, 0.f) + NEG_SLOPE * fminf(zx, 0.f);
        float ry = fmaxf(zy, 0.f) + NEG_SLOPE * fminf(zy, 0.f);
        float rz = fmaxf(zz, 0.f) + NEG_SLOPE * fminf(zz, 0.f);
        float rw = fmaxf(zw, 0.f) + NEG_SLOPE * fminf(zw, 0.f);
        float part = attv.x * rx + attv.y * ry + attv.z * rz + attv.w * rw;
        part += __shfl_xor(part, 1);
        part += __shfl_xor(part, 2);
        part += __shfl_xor(part, 4);
        part += __shfl_xor(part, 8);
        float p = __expf(fminf(part, 60.f));
        l += p;
        O.x = fmaf(p, cur.x, O.x);
        O.y = fmaf(p, cur.y, O.y);
        O.z = fmaf(p, cur.z, O.z);
        O.w = fmaf(p, cur.w, O.w);
    };

    float4 b0 = make_float4(0.f, 0.f, 0.f, 0.f), b1 = b0, b2 = b0, b3 = b0;
    if (0 < total) b0 = ld(0);
    if (1 < total) b1 = ld(1);
    if (2 < total) b2 = ld(2);
    if (3 < total) b3 = ld(3);

    int i = 0;
    for (; i + 4 <= total; i += 4) {
        float4 c0 = b0, c1 = b1, c2 = b2, c3 = b3;
        if (i + 4 < total) b0 = ld(i + 4);
        if (i + 5 < total) b1 = ld(i + 5);
        if (i + 6 < total) b2 = ld(i + 6);
        if (i + 7 < total) b3 = ld(i + 7);
        process(c0);
        process(c1);
        process(c2);
        process(c3);
    }
    const int rem = total - i;
    if (rem > 0) process(b0);
    if (rem > 1) process(b1);
    if (rem > 2) process(b2);

    float inv = (l > 0.f) ? 1.f / l : 0.f;
    float vx = O.x * inv, vy = O.y * inv, vz = O.z * inv, vw = O.w * inv;
    vx += __shfl_xor(vx, 16); vx += __shfl_xor(vx, 32);
    vy += __shfl_xor(vy, 16); vy += __shfl_xor(vy, 32);
    vz += __shfl_xor(vz, 16); vz += __shfl_xor(vz, 32);
    vw += __shfl_xor(vw, 16); vw += __shfl_xor(vw, 32);

    if (lane < 16) {
        float4 r = make_float4(0.25f * vx, 0.25f * vy, 0.25f * vz, 0.25f * vw);
        float4* op = (float4*)(out + (size_t)node * OUT_C);
        if (accumulate) {
            float sg = 1.f / (1.f + __expf(-theta[0]));
            float4 cur = op[lane];
            r.x = fmaf(sg, r.x, cur.x);
            r.y = fmaf(sg, r.y, cur.y);
            r.z = fmaf(sg, r.z, cur.z);
            r.w = fmaf(sg, r.w, cur.w);
        }
        op[lane] = r;
    }
}

// ===========================================================================
// Mixed-grid kernels (co-schedule independent memory- and VALU-bound work)
// ===========================================================================

// mix1: [0,GH) hist both hops (grid-stride) | [GH,GH+gG) gemm Wa | then gemm Wb
__global__ __launch_bounds__(256) void k_mix1(const float* __restrict__ x,
                                              const float* __restrict__ Wa,
                                              float* __restrict__ oa,
                                              const float* __restrict__ Wb,
                                              float* __restrict__ ob, int n,
                                              int GH, int gG,
                                              const int* __restrict__ dst1, int E1,
                                              const int* __restrict__ dst2, int E2,
                                              int* __restrict__ deg) {
    __shared__ float xs[32 * IN_CH];
    const int bx = blockIdx.x;
    if (bx < GH) {
        const int Et = E1 + E2;
        for (int i = bx * 256 + threadIdx.x; i < Et; i += GH * 256) {
            if (i < E1) atomicAdd(&deg[dst1[i]], 1);
            else        atomicAdd(&deg[n + dst2[i - E1]], 1);
        }
    } else {
        int t = bx - GH;
        if (t < gG) dev_gemm(x, Wa, oa, n, t, xs);
        else        dev_gemm(x, Wb, ob, n, t - gG, xs);
    }
}

// mix2: [0,GS) scatter hop (grid-stride) | [GS,GS+gG) gemm Wc
__global__ __launch_bounds__(256) void k_mix2(const float* __restrict__ x,
                                              const float* __restrict__ Wc,
                                              float* __restrict__ oc, int n,
                                              int GS,
                                              const int* __restrict__ src,
                                              const int* __restrict__ dst, int E,
                                              int* cursor, int base,
                                              int* __restrict__ csr) {
    __shared__ float xs[32 * IN_CH];
    const int bx = blockIdx.x;
    if (bx < GS) dev_scatter(src, dst, E, cursor, base, csr, bx, GS);
    else         dev_gemm(x, Wc, oc, n, bx - GS, xs);
}

// mix3: [0,GA) agg | [GA,GA+GS) scatter other hop (GS may be 0 -> pure agg)
__global__ __launch_bounds__(256) void k_mix3(const float* __restrict__ xl,
                                              const float* __restrict__ xr,
                                              const float* __restrict__ att,
                                              const int* __restrict__ offs,
                                              const int* __restrict__ deg,
                                              const int* __restrict__ csr_src,
                                              int n, float* __restrict__ out,
                                              int selfLoop,
                                              const float* __restrict__ theta,
                                              int accumulate, int GA, int GS,
                                              const int* __restrict__ s_src,
                                              const int* __restrict__ s_dst, int s_E,
                                              int* s_cursor, int s_base,
                                              int* __restrict__ s_csr) {
    const int bx = blockIdx.x;
    if (bx < GA)
        dev_agg(xl, xr, att, offs, deg, csr_src, n, out, selfLoop, theta,
                accumulate, bx);
    else if (GS > 0)
        dev_scatter(s_src, s_dst, s_E, s_cursor, s_base, s_csr, bx - GA, GS);
}

// ===========================================================================
// Scan chain (unchanged)
// ===========================================================================
__global__ void k_zero(int* p, int n) {
    int i = blockIdx.x * 256 + threadIdx.x;
    if (i < n) p[i] = 0;
}

__global__ __launch_bounds__(1024) void k_scanA(const int* __restrict__ deg, int n,
                                                int* __restrict__ incl,
                                                int* __restrict__ bsum) {
    __shared__ int sm[1024];
    const int t = threadIdx.x;
    const int i = blockIdx.x * 1024 + t;
    sm[t] = (i < n) ? deg[i] : 0;
    for (int off = 1; off < 1024; off <<= 1) {
        __syncthreads();
        int u = (t >= off) ? sm[t - off] : 0;
        __syncthreads();
        sm[t] += u;
    }
    if (i < n) incl[i] = sm[t];
    if (t == 1023) bsum[blockIdx.x] = sm[1023];
}

__global__ __launch_bounds__(1024) void k_scanB(int* __restrict__ bsum, int nb) {
    __shared__ int sm[1024];
    const int t = threadIdx.x;
    sm[t] = (t < nb) ? bsum[t] : 0;
    for (int off = 1; off < 1024; off <<= 1) {
        __syncthreads();
        int u = (t >= off) ? sm[t - off] : 0;
        __syncthreads();
        sm[t] += u;
    }
    if (t < nb) bsum[t] = sm[t];
}

// incl may alias cursor (same-thread read-before-write); offs distinct.
__global__ void k_scanC(const int* __restrict__ incl, const int* __restrict__ deg,
                        const int* __restrict__ bsum, int n,
                        int* __restrict__ offs, int* cursor) {
    int i = blockIdx.x * 256 + threadIdx.x;
    if (i < n) {
        int b    = i >> 10;
        int base = (b > 0) ? bsum[b - 1] : 0;
        int excl = base + incl[i] - deg[i];
        offs[i]   = excl;
        cursor[i] = excl;
    }
}

// ---------------------------------------------------------------------------
extern "C" void kernel_launch(void* const* d_in, const int* in_sizes, int n_in,
                              void* d_out, int out_size, void* d_ws, size_t ws_size,
                              hipStream_t stream) {
    const float* x     = (const float*)d_in[0];
    const int*   e1    = (const int*)d_in[1];
    const int*   e2    = (const int*)d_in[2];
    const float* Wl    = (const float*)d_in[3];
    const float* Wr0   = (const float*)d_in[4];
    const float* Wr1   = (const float*)d_in[5];
    const float* att0  = (const float*)d_in[6];
    const float* att1  = (const float*)d_in[7];
    const float* theta = (const float*)d_in[8];

    const int n  = in_sizes[0] / IN_CH;  // 50000
    const int E1 = in_sizes[1] / 2;
    const int E2 = in_sizes[2] / 2;
    float* out = (float*)d_out;

    char* w = (char*)d_ws;
    auto alloc = [&](size_t bytes) -> char* {
        char* p = w;
        w += (bytes + 255) & ~(size_t)255;
        return p;
    };
    const size_t projB = (size_t)n * HC * 4;
    const size_t need3 = 3 * ((projB + 255) & ~(size_t)255)
                       + (((size_t)(E1 + E2) * 4 + 255) & ~(size_t)255)
                       + 3 * (((size_t)2 * n * 4 + 255) & ~(size_t)255) + 4096;
    const bool threeBuf = ws_size >= need3;

    float* xl  = (float*)alloc(projB);
    float* xr0 = (float*)alloc(projB);
    float* xr1 = threeBuf ? (float*)alloc(projB) : xr0;
    int* csr    = (int*)alloc((size_t)(E1 + E2) * 4);
    int* deg    = (int*)alloc((size_t)2 * n * 4);
    int* offs   = (int*)alloc((size_t)2 * n * 4);
    int* cursor = (int*)alloc((size_t)2 * n * 4);   // doubles as incl
    int* bsum   = (int*)alloc(4096);

    const int gG    = (n + 31) / 32;     // gemm row-tiles
    const int GA    = (n + 3) / 4;       // agg blocks (4 nodes each)
    const int GH    = 1024;              // hist grid-stride blocks
    const int GS    = 1024;              // scatter grid-stride blocks
    const int n2    = 2 * n;
    const int gN2   = (n2 + 255) / 256;
    const int nScan = (n2 + 1023) / 1024;

    k_zero<<<gN2, 256, 0, stream>>>(deg, n2);

    if (threeBuf) {
        // hist(both hops) || gemm Wl || gemm Wr0
        k_mix1<<<GH + 2 * gG, 256, 0, stream>>>(x, Wl, xl, Wr0, xr0, n, GH, gG,
                                                e1 + E1, E1, e2 + E2, E2, deg);
        k_scanA<<<nScan, 1024, 0, stream>>>(deg, n2, cursor, bsum);
        k_scanB<<<1, 1024, 0, stream>>>(bsum, nScan);
        k_scanC<<<gN2, 256, 0, stream>>>(cursor, deg, bsum, n2, offs, cursor);
        // scatter hop0 || gemm Wr1
        k_mix2<<<GS + gG, 256, 0, stream>>>(x, Wr1, xr1, n, GS,
                                            e1, e1 + E1, E1, cursor, 0, csr);
        // agg hop0 || scatter hop1
        k_mix3<<<GA + GS, 256, 0, stream>>>(xl, xr0, att0, offs, deg, csr, n, out,
                                            1, theta, 0, GA, GS,
                                            e2, e2 + E2, E2, cursor, n, csr);
        // agg hop1
        k_mix3<<<GA, 256, 0, stream>>>(xl, xr1, att1, offs + n, deg + n, csr, n, out,
                                       0, theta, 1, GA, 0,
                                       (const int*)nullptr, (const int*)nullptr, 0,
                                       (int*)nullptr, 0, (int*)nullptr);
    } else {
        // fallback: xr1 aliases xr0 -> Wr1 gemm must follow agg0
        k_mix1<<<GH + 2 * gG, 256, 0, stream>>>(x, Wl, xl, Wr0, xr0, n, GH, gG,
                                                e1 + E1, E1, e2 + E2, E2, deg);
        k_scanA<<<nScan, 1024, 0, stream>>>(deg, n2, cursor, bsum);
        k_scanB<<<1, 1024, 0, stream>>>(bsum, nScan);
        k_scanC<<<gN2, 256, 0, stream>>>(cursor, deg, bsum, n2, offs, cursor);
        k_mix2<<<GS, 256, 0, stream>>>(x, Wr1, xr1, n, GS,
                                       e1, e1 + E1, E1, cursor, 0, csr);  // scatter only
        k_mix3<<<GA + GS, 256, 0, stream>>>(xl, xr0, att0, offs, deg, csr, n, out,
                                            1, theta, 0, GA, GS,
                                            e2, e2 + E2, E2, cursor, n, csr);
        k_mix2<<<gG, 256, 0, stream>>>(x, Wr1, xr0, n, 0,
                                       (const int*)nullptr, (const int*)nullptr, 0,
                                       (int*)nullptr, 0, (int*)nullptr); // gemm only
        k_mix3<<<GA, 256, 0, stream>>>(xl, xr0, att1, offs + n, deg + n, csr, n, out,
                                       0, theta, 1, GA, 0,
                                       (const int*)nullptr, (const int*)nullptr, 0,
                                       (int*)nullptr, 0, (int*)nullptr);
    }
}